// Round 1
// baseline (349.488 us; speedup 1.0000x reference)
//
#include <hip/hip_runtime.h>
#include <math.h>

#define Bsz  64
#define Cch  2048
#define Kdim 768
#define Ssp  361

// ---------------------------------------------------------------------------
// K1: qT[c][b] = dot(text[b,:], W[c,:]) + bias[c]
// grid = 256 blocks x 256 threads; each wave owns 2 channels, W rows cached in
// registers (3 float4 per lane per channel), loops over the 64 batches.
// text (196 KB) is L2-resident across the 64x reuse.
// ---------------------------------------------------------------------------
__global__ __launch_bounds__(256) void k_qgemm(
    const float* __restrict__ text, const float* __restrict__ W,
    const float* __restrict__ bias, float* __restrict__ qT)
{
    const int lane = threadIdx.x & 63;
    const int wv   = threadIdx.x >> 6;
    const int c0   = blockIdx.x * 8 + wv * 2;   // this wave's first channel

    const float4* wA = (const float4*)(W + (size_t)c0 * Kdim);
    const float4* wB = (const float4*)(W + (size_t)(c0 + 1) * Kdim);
    const float4 a0 = wA[lane*3+0], a1 = wA[lane*3+1], a2 = wA[lane*3+2];
    const float4 b0 = wB[lane*3+0], b1 = wB[lane*3+1], b2 = wB[lane*3+2];
    const float biasA = bias[c0], biasB = bias[c0 + 1];

    for (int b = 0; b < Bsz; b++) {
        const float4* t = (const float4*)(text + (size_t)b * Kdim);
        const float4 t0 = t[lane*3+0], t1 = t[lane*3+1], t2 = t[lane*3+2];
        float r0 = a0.x*t0.x + a0.y*t0.y + a0.z*t0.z + a0.w*t0.w
                 + a1.x*t1.x + a1.y*t1.y + a1.z*t1.z + a1.w*t1.w
                 + a2.x*t2.x + a2.y*t2.y + a2.z*t2.z + a2.w*t2.w;
        float r1 = b0.x*t0.x + b0.y*t0.y + b0.z*t0.z + b0.w*t0.w
                 + b1.x*t1.x + b1.y*t1.y + b1.z*t1.z + b1.w*t1.w
                 + b2.x*t2.x + b2.y*t2.y + b2.z*t2.z + b2.w*t2.w;
        #pragma unroll
        for (int off = 32; off; off >>= 1) {
            r0 += __shfl_xor(r0, off);
            r1 += __shfl_xor(r1, off);
        }
        if (lane == 0) {
            qT[(size_t)c0 * Bsz + b]       = r0 + biasA;
            qT[(size_t)(c0 + 1) * Bsz + b] = r1 + biasB;
        }
    }
}

// ---------------------------------------------------------------------------
// K2: partial sims. grid (b=64, cg=16) x 384 threads; thread = spatial s.
// sims_part[b][cg][s] = sum over 128 channels of q[b,c]*img[b,c,s].
// img reads perfectly coalesced (lane = s); q chunk broadcast from LDS.
// No atomics / no zero-init needed: every live entry is written each call.
// ---------------------------------------------------------------------------
__global__ __launch_bounds__(384) void k_sims(
    const float* __restrict__ img, const float* __restrict__ qT,
    float* __restrict__ sims_part)
{
    const int b  = blockIdx.x;
    const int cg = blockIdx.y;
    const int tid = threadIdx.x;

    __shared__ float qL[128];
    if (tid < 128) qL[tid] = qT[(size_t)(cg * 128 + tid) * Bsz + b];
    __syncthreads();

    if (tid < Ssp) {
        const float* base = img + ((size_t)b * Cch + (size_t)cg * 128) * Ssp + tid;
        float acc = 0.f;
        #pragma unroll 8
        for (int c = 0; c < 128; c++)
            acc += qL[c] * base[(size_t)c * Ssp];
        sims_part[((size_t)b * 16 + cg) * Ssp + tid] = acc;
    }
}

// ---------------------------------------------------------------------------
// K3: softmax over s (recomputed per c-chunk from the 16 partials — cheap) +
// weighted pooling. grid (b=64, cg=32) x 256 threads; each wave handles 16 of
// the chunk's 64 channels, coalesced img reads, xor-shuffle reduce.
// ---------------------------------------------------------------------------
__global__ __launch_bounds__(256) void k_pool(
    const float* __restrict__ img, const float* __restrict__ sims_part,
    float* __restrict__ out)
{
    const int b   = blockIdx.x;
    const int cg  = blockIdx.y;
    const int tid = threadIdx.x;
    const int lane = tid & 63;
    const int wv   = tid >> 6;

    __shared__ float w[Ssp];
    __shared__ float red[4];
    __shared__ float outL[64];

    // --- gather final sims values (sum of 16 partials) ---
    float s0 = -1e30f, s1 = -1e30f;
    if (tid < Ssp) {
        float a = 0.f;
        #pragma unroll
        for (int g = 0; g < 16; g++)
            a += sims_part[((size_t)b * 16 + g) * Ssp + tid];
        s0 = a;
    }
    if (tid + 256 < Ssp) {
        float a = 0.f;
        #pragma unroll
        for (int g = 0; g < 16; g++)
            a += sims_part[((size_t)b * 16 + g) * Ssp + tid + 256];
        s1 = a;
    }

    // --- block max ---
    float m = fmaxf(s0, s1);
    #pragma unroll
    for (int off = 32; off; off >>= 1) m = fmaxf(m, __shfl_xor(m, off));
    if (lane == 0) red[wv] = m;
    __syncthreads();
    m = fmaxf(fmaxf(red[0], red[1]), fmaxf(red[2], red[3]));

    // --- exp + block sum ---
    const float e0 = (tid < Ssp)       ? __expf(s0 - m) : 0.f;
    const float e1 = (tid + 256 < Ssp) ? __expf(s1 - m) : 0.f;
    if (tid < Ssp)       w[tid]       = e0;
    if (tid + 256 < Ssp) w[tid + 256] = e1;
    float l = e0 + e1;
    #pragma unroll
    for (int off = 32; off; off >>= 1) l += __shfl_xor(l, off);
    __syncthreads();              // everyone done reading red (max) + w ready
    if (lane == 0) red[wv] = l;
    __syncthreads();
    const float inv = 1.f / (red[0] + red[1] + red[2] + red[3]);

    // --- weighted pooling: wave per channel ---
    for (int c = wv; c < 64; c += 4) {
        const float* base = img + ((size_t)b * Cch + (size_t)cg * 64 + c) * Ssp;
        float p = 0.f;
        #pragma unroll
        for (int j = 0; j < 5; j++)
            p += base[lane + 64 * j] * w[lane + 64 * j];
        if (lane + 320 < Ssp)
            p += base[lane + 320] * w[lane + 320];
        #pragma unroll
        for (int off = 32; off; off >>= 1) p += __shfl_xor(p, off);
        if (lane == 0) outL[c] = p;
    }
    __syncthreads();
    if (tid < 64)
        out[(size_t)b * Cch + (size_t)cg * 64 + tid] = outL[tid] * inv;
}

// ---------------------------------------------------------------------------
extern "C" void kernel_launch(void* const* d_in, const int* in_sizes, int n_in,
                              void* d_out, int out_size, void* d_ws, size_t ws_size,
                              hipStream_t stream) {
    const float* text = (const float*)d_in[0];   // [64, 768]
    const float* img  = (const float*)d_in[1];   // [64, 2048, 19, 19]
    const float* W    = (const float*)d_in[2];   // [2048, 768]
    const float* bias = (const float*)d_in[3];   // [2048]
    float* out = (float*)d_out;                  // [64, 2048]

    // workspace: qT (2048*64 fp32 = 512 KB) + sims_part (64*16*361 fp32 = 1.41 MB)
    float* qT        = (float*)d_ws;
    float* sims_part = qT + (size_t)Cch * Bsz;

    k_qgemm<<<dim3(Cch / 8), 256, 0, stream>>>(text, W, bias, qT);
    k_sims <<<dim3(Bsz, 16), 384, 0, stream>>>(img, qT, sims_part);
    k_pool <<<dim3(Bsz, 32), 256, 0, stream>>>(img, sims_part, out);
}

// Round 2
// 318.682 us; speedup vs baseline: 1.0967x; 1.0967x over previous
//
#include <hip/hip_runtime.h>
#include <math.h>

#define Bsz  64
#define Cch  2048
#define Kdim 768
#define Ssp  361

// ---------------------------------------------------------------------------
// K1: qT[c][b] = dot(text[b,:], W[c,:]) + bias[c]
// grid = (256, 4) x 256 threads; wave owns 2 channels (W rows in 24 VGPRs),
// block-row y handles 16 of the 64 batches -> 4 waves/SIMD hide the
// text-load + shuffle-reduce latency chain. W re-read x4 (24 MB, L2/L3).
// ---------------------------------------------------------------------------
__global__ __launch_bounds__(256) void k_qgemm(
    const float* __restrict__ text, const float* __restrict__ W,
    const float* __restrict__ bias, float* __restrict__ qT)
{
    const int lane = threadIdx.x & 63;
    const int wv   = threadIdx.x >> 6;
    const int c0   = blockIdx.x * 8 + wv * 2;   // this wave's first channel
    const int b0   = blockIdx.y * 16;           // this block-row's batches

    const float4* wA = (const float4*)(W + (size_t)c0 * Kdim);
    const float4* wB = (const float4*)(W + (size_t)(c0 + 1) * Kdim);
    const float4 a0 = wA[lane*3+0], a1 = wA[lane*3+1], a2 = wA[lane*3+2];
    const float4 b0v = wB[lane*3+0], b1v = wB[lane*3+1], b2v = wB[lane*3+2];
    const float biasA = bias[c0], biasB = bias[c0 + 1];

    for (int b = b0; b < b0 + 16; b++) {
        const float4* t = (const float4*)(text + (size_t)b * Kdim);
        const float4 t0 = t[lane*3+0], t1 = t[lane*3+1], t2 = t[lane*3+2];
        float r0 = a0.x*t0.x + a0.y*t0.y + a0.z*t0.z + a0.w*t0.w
                 + a1.x*t1.x + a1.y*t1.y + a1.z*t1.z + a1.w*t1.w
                 + a2.x*t2.x + a2.y*t2.y + a2.z*t2.z + a2.w*t2.w;
        float r1 = b0v.x*t0.x + b0v.y*t0.y + b0v.z*t0.z + b0v.w*t0.w
                 + b1v.x*t1.x + b1v.y*t1.y + b1v.z*t1.z + b1v.w*t1.w
                 + b2v.x*t2.x + b2v.y*t2.y + b2v.z*t2.z + b2v.w*t2.w;
        #pragma unroll
        for (int off = 32; off; off >>= 1) {
            r0 += __shfl_xor(r0, off);
            r1 += __shfl_xor(r1, off);
        }
        if (lane == 0) {
            qT[(size_t)c0 * Bsz + b]       = r0 + biasA;
            qT[(size_t)(c0 + 1) * Bsz + b] = r1 + biasB;
        }
    }
}

// ---------------------------------------------------------------------------
// K2: partial sims. grid (b=64, cg=16) x 384 threads; thread = spatial s.
// sims_part[b][cg][s] = sum over 128 channels of q[b,c]*img[b,c,s].
// img reads perfectly coalesced (lane = s); q chunk broadcast from LDS.
// This is the HBM-streaming pass (189 MB) — expected at BW ceiling.
// ---------------------------------------------------------------------------
__global__ __launch_bounds__(384) void k_sims(
    const float* __restrict__ img, const float* __restrict__ qT,
    float* __restrict__ sims_part)
{
    const int b  = blockIdx.x;
    const int cg = blockIdx.y;
    const int tid = threadIdx.x;

    __shared__ float qL[128];
    if (tid < 128) qL[tid] = qT[(size_t)(cg * 128 + tid) * Bsz + b];
    __syncthreads();

    if (tid < Ssp) {
        const float* base = img + ((size_t)b * Cch + (size_t)cg * 128) * Ssp + tid;
        float acc = 0.f;
        #pragma unroll 8
        for (int c = 0; c < 128; c++)
            acc += qL[c] * base[(size_t)c * Ssp];
        sims_part[((size_t)b * 16 + cg) * Ssp + tid] = acc;
    }
}

// ---------------------------------------------------------------------------
// K3: weights. grid = 64 blocks x 384 threads; thread = spatial s.
// Sums the 16 partials, block softmax, writes PRE-NORMALIZED weights
// (already divided by the denominator) so k_pool is a pure dot-product.
// ---------------------------------------------------------------------------
__global__ __launch_bounds__(384) void k_wts(
    const float* __restrict__ sims_part, float* __restrict__ wts)
{
    const int b   = blockIdx.x;
    const int tid = threadIdx.x;
    const int lane = tid & 63;
    const int wv   = tid >> 6;

    __shared__ float red[6];

    float s0 = -1e30f;
    if (tid < Ssp) {
        float a = 0.f;
        #pragma unroll
        for (int g = 0; g < 16; g++)
            a += sims_part[((size_t)b * 16 + g) * Ssp + tid];
        s0 = a;
    }

    // block max
    float m = s0;
    #pragma unroll
    for (int off = 32; off; off >>= 1) m = fmaxf(m, __shfl_xor(m, off));
    if (lane == 0) red[wv] = m;
    __syncthreads();
    m = red[0];
    #pragma unroll
    for (int w = 1; w < 6; w++) m = fmaxf(m, red[w]);
    __syncthreads();   // everyone done reading red before reuse

    // exp + block sum
    const float e0 = (tid < Ssp) ? __expf(s0 - m) : 0.f;
    float l = e0;
    #pragma unroll
    for (int off = 32; off; off >>= 1) l += __shfl_xor(l, off);
    if (lane == 0) red[wv] = l;
    __syncthreads();
    l = red[0] + red[1] + red[2] + red[3] + red[4] + red[5];

    if (tid < Ssp)
        wts[(size_t)b * Ssp + tid] = e0 / l;
}

// ---------------------------------------------------------------------------
// K4: weighted pooling. grid (b=64, cg=32) x 256 threads; wave per channel,
// coalesced img reads (second pass — expected L3-resident), shuffle reduce,
// coalesced 64-wide store via LDS gather. Weights pre-normalized.
// ---------------------------------------------------------------------------
__global__ __launch_bounds__(256) void k_pool(
    const float* __restrict__ img, const float* __restrict__ wts,
    float* __restrict__ out)
{
    const int b   = blockIdx.x;
    const int cg  = blockIdx.y;
    const int tid = threadIdx.x;
    const int lane = tid & 63;
    const int wv   = tid >> 6;

    __shared__ float w[Ssp];
    __shared__ float outL[64];

    if (tid < Ssp)       w[tid]       = wts[(size_t)b * Ssp + tid];
    if (tid + 256 < Ssp) w[tid + 256] = wts[(size_t)b * Ssp + tid + 256];
    __syncthreads();

    for (int c = wv; c < 64; c += 4) {
        const float* base = img + ((size_t)b * Cch + (size_t)cg * 64 + c) * Ssp;
        float p = 0.f;
        #pragma unroll
        for (int j = 0; j < 5; j++)
            p += base[lane + 64 * j] * w[lane + 64 * j];
        if (lane + 320 < Ssp)
            p += base[lane + 320] * w[lane + 320];
        #pragma unroll
        for (int off = 32; off; off >>= 1) p += __shfl_xor(p, off);
        if (lane == 0) outL[c] = p;
    }
    __syncthreads();
    if (tid < 64)
        out[(size_t)b * Cch + (size_t)cg * 64 + tid] = outL[tid];
}

// ---------------------------------------------------------------------------
extern "C" void kernel_launch(void* const* d_in, const int* in_sizes, int n_in,
                              void* d_out, int out_size, void* d_ws, size_t ws_size,
                              hipStream_t stream) {
    const float* text = (const float*)d_in[0];   // [64, 768]
    const float* img  = (const float*)d_in[1];   // [64, 2048, 19, 19]
    const float* W    = (const float*)d_in[2];   // [2048, 768]
    const float* bias = (const float*)d_in[3];   // [2048]
    float* out = (float*)d_out;                  // [64, 2048]

    // ws: qT (2048*64) + sims_part (64*16*361) + wts (64*361), all fp32
    float* qT        = (float*)d_ws;
    float* sims_part = qT + (size_t)Cch * Bsz;
    float* wts       = sims_part + (size_t)Bsz * 16 * Ssp;

    k_qgemm<<<dim3(256, 4), 256, 0, stream>>>(text, W, bias, qT);
    k_sims <<<dim3(Bsz, 16), 384, 0, stream>>>(img, qT, sims_part);
    k_wts  <<<dim3(Bsz),     384, 0, stream>>>(sims_part, wts);
    k_pool <<<dim3(Bsz, 32), 256, 0, stream>>>(img, wts, out);
}